// Round 8
// baseline (577.729 us; speedup 1.0000x reference)
//
#include <hip/hip_runtime.h>
#include <hip/hip_bf16.h>
#include <cstdint>

#define B_SZ 4
#define T_SZ 2048
#define C_SZ 1024
#define H_SZ 16
#define D_SZ 64
#define BT_SZ (B_SZ * T_SZ)     // 8192
#define C3_SZ (3 * C_SZ)        // 3072
#define NKC (C_SZ / 32)         // 32 K-chunks

typedef __attribute__((ext_vector_type(8))) short bf16x8;
typedef __attribute__((ext_vector_type(4))) float f32x4;
typedef __attribute__((ext_vector_type(4))) unsigned short ushort4v;
typedef __attribute__((ext_vector_type(4))) unsigned int uint4v;

typedef __attribute__((address_space(3))) unsigned int lds_u32;
typedef __attribute__((address_space(1))) const unsigned int glb_u32;

__device__ __forceinline__ unsigned short f2bf(float f) {
  unsigned u = __builtin_bit_cast(unsigned, f);
  u += 0x7fffu + ((u >> 16) & 1u);  // round-to-nearest-even
  return (unsigned short)(u >> 16);
}

// pack two fp32 -> two bf16 (truncating) in ONE v_perm_b32
__device__ __forceinline__ unsigned packbf2(float lo, float hi) {
  return __builtin_amdgcn_perm(__builtin_bit_cast(unsigned, hi),
                               __builtin_bit_cast(unsigned, lo), 0x07060302u);
}

// async global->LDS, 16B per lane; LDS dest = wave-uniform base + lane*16
__device__ __forceinline__ void gll16(const unsigned short* g,
                                      unsigned short* l) {
  __builtin_amdgcn_global_load_lds((glb_u32*)g, (lds_u32*)l, 16, 0, 0);
}

// ===========================================================================
// Fragment layouts (verified rounds 2-7):
//  A-frag blocked: elem(r,k) -> ((tb*NKC+kc)*4+quad)*128 + (r&15)*8 + (k&7)
//  B-frag blocked: same with n = c&15
//  Vf key-permuted PV B-operand: elem(t,d) -> ((gb*4+dv)*4+quad)*128
//      + (d&15)*8 + j,  kk=t&31, quad=(kk>>2)&3, j=(kk>>4)*4+(kk&3)
// ===========================================================================

// ---------------------------------------------------------------------------
// pack_all: fused pack_x + pack_w(W_attn) + pack_w(W_proj)
// ---------------------------------------------------------------------------
__device__ __forceinline__ void pack_x_task(const float* __restrict__ x,
                                            unsigned short* __restrict__ Af,
                                            int task, int lane) {
  const int quad = lane >> 4, n = lane & 15;
  const int tb = task >> 5, kc = task & 31;
  const float* src = x + (size_t)(tb * 16 + n) * C_SZ + kc * 32 + quad * 8;
  float4 a = *(const float4*)src;
  float4 b = *(const float4*)(src + 4);
  ushort4v o0, o1;
  o0[0] = f2bf(a.x); o0[1] = f2bf(a.y); o0[2] = f2bf(a.z); o0[3] = f2bf(a.w);
  o1[0] = f2bf(b.x); o1[1] = f2bf(b.y); o1[2] = f2bf(b.z); o1[3] = f2bf(b.w);
  unsigned short* dst = Af + ((size_t)((tb * NKC + kc) * 4 + quad) * 16 + n) * 8;
  *(ushort4v*)dst = o0;
  *(ushort4v*)(dst + 4) = o1;
}

__device__ __forceinline__ void pack_w_task(const float* __restrict__ W,
                                            unsigned short* __restrict__ Wb,
                                            int N, int task, int lane) {
  const int quad = lane >> 4, n = lane & 15;
  const int nt = task >> 5, kc = task & 31;
  const int col = nt * 16 + n;
  const int k0 = kc * 32 + quad * 8;
  ushort4v o0, o1;
#pragma unroll
  for (int i = 0; i < 4; ++i) o0[i] = f2bf(W[(size_t)(k0 + i) * N + col]);
#pragma unroll
  for (int i = 0; i < 4; ++i) o1[i] = f2bf(W[(size_t)(k0 + 4 + i) * N + col]);
  unsigned short* dst = Wb + ((size_t)((nt * NKC + kc) * 4 + quad) * 16 + n) * 8;
  *(ushort4v*)dst = o0;
  *(ushort4v*)(dst + 4) = o1;
}

__global__ __launch_bounds__(256) void pack_all(
    const float* __restrict__ x, const float* __restrict__ Wa,
    const float* __restrict__ Wp, unsigned short* __restrict__ Af,
    unsigned short* __restrict__ Wab, unsigned short* __restrict__ Wpb) {
  const int bx = blockIdx.x;
  const int sub = threadIdx.x >> 6;
  const int lane = threadIdx.x & 63;
  if (bx < 4096) {
    pack_x_task(x, Af, bx * 4 + sub, lane);              // 512 tb x 32 kc
  } else if (bx < 4096 + 1536) {
    pack_w_task(Wa, Wab, C3_SZ, (bx - 4096) * 4 + sub, lane);  // 192 nt x 32
  } else {
    pack_w_task(Wp, Wpb, C_SZ, (bx - 5632) * 4 + sub, lane);   // 64 nt x 32
  }
}

// ---------------------------------------------------------------------------
// m97-style staged GEMM mainloop (verified round 6): 128x128 tile, BK=64,
// global_load_lds(16B) into an LDS image of the fragment-blocked layout.
// ---------------------------------------------------------------------------
__device__ __forceinline__ void gemm128_mainloop(
    const unsigned short* __restrict__ A, const unsigned short* __restrict__ B,
    int tbB, int ntB, unsigned short* smem, f32x4 acc[4][4]) {
  const int tid = threadIdx.x;
  const int w = tid >> 6, lane = tid & 63;
  const int quad = lane >> 4, n = lane & 15;
  const int wr = w >> 1, wc = w & 1;
  unsigned short* smemA = smem;         // 8192 shorts
  unsigned short* smemB = smem + 8192;  // 8192 shorts

  for (int kc0 = 0; kc0 < NKC; kc0 += 2) {
#pragma unroll
    for (int i2 = 0; i2 < 2; ++i2) {
      const int i = 2 * w + i2;
      const unsigned short* gA =
          A + ((size_t)(tbB + i) * NKC + kc0) * 512 + lane * 8;
      const unsigned short* gB =
          B + ((size_t)(ntB + i) * NKC + kc0) * 512 + lane * 8;
      gll16(gA, smemA + i * 1024);
      gll16(gA + 512, smemA + i * 1024 + 512);
      gll16(gB, smemB + i * 1024);
      gll16(gB + 512, smemB + i * 1024 + 512);
    }
    __syncthreads();
#pragma unroll
    for (int kcl = 0; kcl < 2; ++kcl) {
      bf16x8 af[4], bfr[4];
#pragma unroll
      for (int m = 0; m < 4; ++m)
        af[m] = *(const bf16x8*)(smemA + (wr * 4 + m) * 1024 +
                                 (kcl * 4 + quad) * 128 + n * 8);
#pragma unroll
      for (int nn = 0; nn < 4; ++nn)
        bfr[nn] = *(const bf16x8*)(smemB + (wc * 4 + nn) * 1024 +
                                   (kcl * 4 + quad) * 128 + n * 8);
#pragma unroll
      for (int m = 0; m < 4; ++m)
#pragma unroll
        for (int nn = 0; nn < 4; ++nn)
          acc[m][nn] = __builtin_amdgcn_mfma_f32_16x16x32_bf16(
              af[m], bfr[nn], acc[m][nn], 0, 0, 0);
    }
    __syncthreads();
  }
}

// qkv: 1-D grid 1536, XCD-aware swizzle — each XCD (f&7) owns 8 consecutive
// by rows; bx varies fastest so the 2 MB Af row stays hot in that XCD's L2
// while Wab streams.
__global__ __launch_bounds__(256) void qkv_mfma(
    const unsigned short* __restrict__ Af, const unsigned short* __restrict__ Wab,
    const float* __restrict__ bias, unsigned short* __restrict__ Qf,
    unsigned short* __restrict__ Kf, unsigned short* __restrict__ Vf) {
  __shared__ unsigned short smem[16384];
  const int tid = threadIdx.x;
  const int w = tid >> 6, lane = tid & 63;
  const int quad = lane >> 4, n = lane & 15;
  const int wr = w >> 1, wc = w & 1;
  const int f = blockIdx.x;
  const int xcd = f & 7, i = f >> 3;
  const int by = xcd * 8 + (i / 24);   // [0,64)
  const int bx = i % 24;               // [0,24)
  f32x4 acc[4][4];
#pragma unroll
  for (int m = 0; m < 4; ++m)
#pragma unroll
    for (int nn = 0; nn < 4; ++nn) acc[m][nn] = (f32x4){0.f, 0.f, 0.f, 0.f};

  gemm128_mainloop(Af, Wab, by * 8, bx * 8, smem, acc);

  const int cb = bx * 128 + wc * 64;
  const int which = cb >> 10;
  const int h = (cb & 1023) >> 6;
  const int gr0 = by * 128 + wr * 64;
  const int b = gr0 >> 11;
  const int t0 = gr0 & 2047;
  const size_t bhoff = (size_t)(b * H_SZ + h) * (T_SZ * D_SZ);
  float bfl[4];
#pragma unroll
  for (int nn = 0; nn < 4; ++nn) bfl[nn] = bias[cb + nn * 16 + n];

  if (which < 2) {
    unsigned short* dst = ((which == 0) ? Qf : Kf) + bhoff;
    // Q carries 1/sqrt(D) AND log2(e): softmax exp becomes a bare v_exp_f32
    const float scl = (which == 0) ? 0.18033688f : 1.0f;
#pragma unroll
    for (int m = 0; m < 4; ++m) {
      const int tb = (t0 + m * 16) >> 4;
#pragma unroll
      for (int nn = 0; nn < 4; ++nn) {
        const int dc = nn >> 1;
        const int qd = (nn & 1) * 2 + (n >> 3);
        const int jq = n & 7;
#pragma unroll
        for (int r = 0; r < 4; ++r) {
          const int nq = quad * 4 + r;
          dst[((size_t)((tb * 2 + dc) * 4 + qd)) * 128 + nq * 8 + jq] =
              f2bf((acc[m][nn][r] + bfl[nn]) * scl);
        }
      }
    }
  } else {
    unsigned short* dst = Vf + bhoff;
    const int gb0 = t0 >> 5;
#pragma unroll
    for (int m = 0; m < 4; ++m) {
      const int gb = gb0 + (m >> 1);
#pragma unroll
      for (int nn = 0; nn < 4; ++nn) {
#pragma unroll
        for (int r = 0; r < 4; ++r) {
          dst[((size_t)((gb * 4 + nn) * 4 + quad)) * 128 + n * 8 + (m & 1) * 4 + r] =
              f2bf(acc[m][nn][r] + bfl[nn]);
        }
      }
    }
  }
}

// proj: 1-D grid 512, same XCD swizzle (xcd owns 8 by rows, bx inner).
__global__ __launch_bounds__(256) void proj_mfma(
    const unsigned short* __restrict__ Yf, const unsigned short* __restrict__ Wpb,
    const float* __restrict__ bias, float* __restrict__ out) {
  __shared__ unsigned short smem[16384];
  const int tid = threadIdx.x;
  const int w = tid >> 6, lane = tid & 63;
  const int quad = lane >> 4, n = lane & 15;
  const int wr = w >> 1, wc = w & 1;
  const int f = blockIdx.x;
  const int xcd = f & 7, i = f >> 3;
  const int by = xcd * 8 + (i / 8);    // [0,64)
  const int bx = i % 8;                // [0,8)
  f32x4 acc[4][4];
#pragma unroll
  for (int m = 0; m < 4; ++m)
#pragma unroll
    for (int nn = 0; nn < 4; ++nn) acc[m][nn] = (f32x4){0.f, 0.f, 0.f, 0.f};

  gemm128_mainloop(Yf, Wpb, by * 8, bx * 8, smem, acc);

  const int cb = bx * 128 + wc * 64;
  const int gr0 = by * 128 + wr * 64;
  float bfl[4];
#pragma unroll
  for (int nn = 0; nn < 4; ++nn) bfl[nn] = bias[cb + nn * 16 + n];
#pragma unroll
  for (int m = 0; m < 4; ++m)
#pragma unroll
    for (int nn = 0; nn < 4; ++nn)
#pragma unroll
      for (int r = 0; r < 4; ++r)
        out[(size_t)(gr0 + m * 16 + quad * 4 + r) * C_SZ + cb + nn * 16 + n] =
            acc[m][nn][r] + bfl[nn];
}

// ---------------------------------------------------------------------------
// attn_mfma v6: v5 + (a) __launch_bounds__(64,4) caps VGPR at 128 -> 16
// waves/CU (was 12); (b) V-prefetch into dead vfr after m=3's PV, matching
// the K-prefetch; K0/V0 preloaded, diagonal tile fully load-free.
// ---------------------------------------------------------------------------
__global__ __launch_bounds__(64, 4) void attn_mfma(
    const unsigned short* __restrict__ Qf,
    const unsigned short* __restrict__ Kf,
    const unsigned short* __restrict__ Vf, unsigned short* __restrict__ Yf) {
  const int lane = threadIdx.x;
  const int quad = lane >> 4;
  const int n = lane & 15;
  const int bx = blockIdx.x;
  const int qt = 31 - (bx >> 6);  // long blocks dispatch first
  const int bh = bx & 63;
  const int b = bh >> 4, h = bh & 15;
  const int wq0 = qt * 64;
  const size_t bhoff = (size_t)bh * (T_SZ * D_SZ);
  const bf16x8* Qp = (const bf16x8*)(Qf + bhoff);
  const bf16x8* Kp = (const bf16x8*)(Kf + bhoff);
  const bf16x8* Vp = (const bf16x8*)(Vf + bhoff);

  bf16x8 qfr[4][2];
#pragma unroll
  for (int m = 0; m < 4; ++m) {
    const int tb = (wq0 >> 4) + m;
#pragma unroll
    for (int dc = 0; dc < 2; ++dc)
      qfr[m][dc] = Qp[((tb * 2 + dc) * 4 + quad) * 16 + n];
  }

  bf16x8 kfr[4][2], vfr[2][4];
  f32x4 O[4][4];
  f32x4 ls[4];
#pragma unroll
  for (int m = 0; m < 4; ++m) {
    ls[m] = (f32x4){0.f, 0.f, 0.f, 0.f};
#pragma unroll
    for (int dv = 0; dv < 4; ++dv) O[m][dv] = (f32x4){0.f, 0.f, 0.f, 0.f};
  }

  // preload K and V for tile 0
#pragma unroll
  for (int s = 0; s < 4; ++s) {
    kfr[s][0] = Kp[((s * 2 + 0) * 4 + quad) * 16 + n];
    kfr[s][1] = Kp[((s * 2 + 1) * 4 + quad) * 16 + n];
  }
#pragma unroll
  for (int g = 0; g < 2; ++g)
#pragma unroll
    for (int dv = 0; dv < 4; ++dv)
      vfr[g][dv] = Vp[((g * 4 + dv) * 4 + quad) * 16 + n];

  // ---- full (unmasked) k-tiles ----
  for (int kt = 0; kt < qt; ++kt) {
#pragma unroll
    for (int m = 0; m < 4; ++m) {
      f32x4 st[4];
#pragma unroll
      for (int s = 0; s < 4; ++s) {
        f32x4 z = {0.f, 0.f, 0.f, 0.f};
        z = __builtin_amdgcn_mfma_f32_16x16x32_bf16(kfr[s][0], qfr[m][0], z, 0, 0, 0);
        z = __builtin_amdgcn_mfma_f32_16x16x32_bf16(kfr[s][1], qfr[m][1], z, 0, 0, 0);
        st[s] = z;
      }
      if (m == 3) {
        // kfr dead for this tile: prefetch K for tile kt+1 (maybe diagonal)
        const int tb0 = (kt + 1) * 4;
#pragma unroll
        for (int s = 0; s < 4; ++s) {
          kfr[s][0] = Kp[(((tb0 + s) * 2 + 0) * 4 + quad) * 16 + n];
          kfr[s][1] = Kp[(((tb0 + s) * 2 + 1) * 4 + quad) * 16 + n];
        }
      }
      uint4v pw[2];
#pragma unroll
      for (int s = 0; s < 4; ++s) {
        float pr[4];
#pragma unroll
        for (int r = 0; r < 4; ++r) {
          pr[r] = __builtin_amdgcn_exp2f(st[s][r]);
          ls[m][r] += pr[r];
        }
        pw[s >> 1][(s & 1) * 2 + 0] = packbf2(pr[0], pr[1]);
        pw[s >> 1][(s & 1) * 2 + 1] = packbf2(pr[2], pr[3]);
      }
#pragma unroll
      for (int g = 0; g < 2; ++g) {
        const bf16x8 pg = __builtin_bit_cast(bf16x8, pw[g]);
#pragma unroll
        for (int dv = 0; dv < 4; ++dv)
          O[m][dv] = __builtin_amdgcn_mfma_f32_16x16x32_bf16(
              pg, vfr[g][dv], O[m][dv], 0, 0, 0);
      }
      if (m == 3) {
        // vfr dead after this tile's last PV: prefetch V for tile kt+1
        const int gb0 = (kt + 1) * 2;
#pragma unroll
        for (int g = 0; g < 2; ++g)
#pragma unroll
          for (int dv = 0; dv < 4; ++dv)
            vfr[g][dv] = Vp[(((gb0 + g) * 4 + dv) * 4 + quad) * 16 + n];
      }
    }
  }

  // ---- diagonal k-tile (kt == qt): kfr/vfr already resident ----
  {
#pragma unroll
    for (int m = 0; m < 4; ++m) {
      f32x4 st[4];
#pragma unroll
      for (int s = 0; s < 4; ++s) {
        f32x4 z = {0.f, 0.f, 0.f, 0.f};
        if (s <= m) {
          z = __builtin_amdgcn_mfma_f32_16x16x32_bf16(kfr[s][0], qfr[m][0], z, 0, 0, 0);
          z = __builtin_amdgcn_mfma_f32_16x16x32_bf16(kfr[s][1], qfr[m][1], z, 0, 0, 0);
        }
        st[s] = z;
      }
      uint4v pw[2] = {(uint4v){0, 0, 0, 0}, (uint4v){0, 0, 0, 0}};
#pragma unroll
      for (int s = 0; s < 4; ++s) {
        if (s <= m) {
          float pr[4];
#pragma unroll
          for (int r = 0; r < 4; ++r) {
            float v = st[s][r];
            if (s == m && quad * 4 + r > n) v = -1e30f;  // key > query
            pr[r] = __builtin_amdgcn_exp2f(v);
            ls[m][r] += pr[r];
          }
          pw[s >> 1][(s & 1) * 2 + 0] = packbf2(pr[0], pr[1]);
          pw[s >> 1][(s & 1) * 2 + 1] = packbf2(pr[2], pr[3]);
        }
      }
#pragma unroll
      for (int g = 0; g < 2; ++g) {
        if (g * 2 <= m) {
          const bf16x8 pg = __builtin_bit_cast(bf16x8, pw[g]);
#pragma unroll
          for (int dv = 0; dv < 4; ++dv)
            O[m][dv] = __builtin_amdgcn_mfma_f32_16x16x32_bf16(
                pg, vfr[g][dv], O[m][dv], 0, 0, 0);
        }
      }
    }
  }

  // ---- single deferred row-sum reduction + epilogue (bf16 A-frag Yf) ----
#pragma unroll
  for (int m = 0; m < 4; ++m) {
    float lt = ls[m][0] + ls[m][1] + ls[m][2] + ls[m][3];
    lt += __shfl_xor(lt, 16);
    lt += __shfl_xor(lt, 32);
    const float inv = 1.0f / lt;
    float iv[4];
#pragma unroll
    for (int r = 0; r < 4; ++r) iv[r] = __shfl(inv, quad * 4 + r);
    const int tb = (b * T_SZ + wq0 + m * 16) >> 4;
#pragma unroll
    for (int dv = 0; dv < 4; ++dv) {
      const int kc = h * 2 + (dv >> 1);
      const int qa = (dv & 1) * 2 + (n >> 3);
      const int ja = n & 7;
#pragma unroll
      for (int r = 0; r < 4; ++r) {
        const int na = quad * 4 + r;
        Yf[((size_t)((tb * NKC + kc) * 4 + qa)) * 128 + na * 8 + ja] =
            f2bf(O[m][dv][r] * iv[r]);
      }
    }
  }
}

// ---------------------------------------------------------------------------
extern "C" void kernel_launch(void* const* d_in, const int* in_sizes, int n_in,
                              void* d_out, int out_size, void* d_ws,
                              size_t ws_size, hipStream_t stream) {
  const float* x = (const float*)d_in[0];
  const float* W_attn = (const float*)d_in[1];
  const float* b_attn = (const float*)d_in[2];
  const float* W_proj = (const float*)d_in[3];
  const float* b_proj = (const float*)d_in[4];
  float* out = (float*)d_out;

  const size_t perbf = (size_t)B_SZ * H_SZ * T_SZ * D_SZ;  // 8M elems
  unsigned short* Af = (unsigned short*)d_ws;              // 16 MB
  unsigned short* Wab = Af + (size_t)BT_SZ * C_SZ;         // 6 MB
  unsigned short* Wpb = Wab + (size_t)C_SZ * C3_SZ;        // 2 MB
  unsigned short* Qf = Wpb + (size_t)C_SZ * C_SZ;          // 16 MB
  unsigned short* Kf = Qf + perbf;                         // 16 MB
  unsigned short* Vf = Kf + perbf;                         // 16 MB
  unsigned short* Yf = Vf + perbf;                         // 16 MB

  pack_all<<<6144, 256, 0, stream>>>(x, W_attn, W_proj, Af, Wab, Wpb);
  qkv_mfma<<<1536, 256, 0, stream>>>(Af, Wab, b_attn, Qf, Kf, Vf);
  attn_mfma<<<dim3(32 * B_SZ * H_SZ), 64, 0, stream>>>(Qf, Kf, Vf, Yf);
  proj_mfma<<<512, 256, 0, stream>>>(Yf, Wpb, b_proj, out);
}

// Round 9
// 223.101 us; speedup vs baseline: 2.5895x; 2.5895x over previous
//
#include <hip/hip_runtime.h>
#include <hip/hip_bf16.h>
#include <cstdint>

#define B_SZ 4
#define T_SZ 2048
#define C_SZ 1024
#define H_SZ 16
#define D_SZ 64
#define BT_SZ (B_SZ * T_SZ)     // 8192
#define C3_SZ (3 * C_SZ)        // 3072
#define NKC (C_SZ / 32)         // 32 K-chunks

typedef __attribute__((ext_vector_type(8))) short bf16x8;
typedef __attribute__((ext_vector_type(4))) float f32x4;
typedef __attribute__((ext_vector_type(4))) unsigned short ushort4v;
typedef __attribute__((ext_vector_type(4))) unsigned int uint4v;

typedef __attribute__((address_space(3))) unsigned int lds_u32;
typedef __attribute__((address_space(1))) const unsigned int glb_u32;

__device__ __forceinline__ unsigned short f2bf(float f) {
  unsigned u = __builtin_bit_cast(unsigned, f);
  u += 0x7fffu + ((u >> 16) & 1u);  // round-to-nearest-even
  return (unsigned short)(u >> 16);
}

// pack two fp32 -> two bf16 (truncating) in ONE v_perm_b32
__device__ __forceinline__ unsigned packbf2(float lo, float hi) {
  return __builtin_amdgcn_perm(__builtin_bit_cast(unsigned, hi),
                               __builtin_bit_cast(unsigned, lo), 0x07060302u);
}

// async global->LDS, 16B per lane; LDS dest = wave-uniform base + lane*16
__device__ __forceinline__ void gll16(const unsigned short* g,
                                      unsigned short* l) {
  __builtin_amdgcn_global_load_lds((glb_u32*)g, (lds_u32*)l, 16, 0, 0);
}

// ===========================================================================
// Fragment layouts (verified rounds 2-7):
//  A-frag blocked: elem(r,k) -> ((tb*NKC+kc)*4+quad)*128 + (r&15)*8 + (k&7)
//  B-frag blocked: same with n = c&15
//  Vf key-permuted PV B-operand: elem(t,d) -> ((gb*4+dv)*4+quad)*128
//      + (d&15)*8 + j,  kk=t&31, quad=(kk>>2)&3, j=(kk>>4)*4+(kk&3)
//
// NOTE (round 8 lesson): NEVER cap this family of register-heavy MFMA
// kernels with __launch_bounds__ min-waves on gfx950 — the unified
// VGPR/AGPR file makes the compiler split 64/64 and spill the whole
// accumulator to scratch (1.6 GB HBM traffic, 6x slowdown).
// ===========================================================================

// ---------------------------------------------------------------------------
// pack_all: fused pack_x + pack_w(W_attn) + pack_w(W_proj)
// ---------------------------------------------------------------------------
__device__ __forceinline__ void pack_x_task(const float* __restrict__ x,
                                            unsigned short* __restrict__ Af,
                                            int task, int lane) {
  const int quad = lane >> 4, n = lane & 15;
  const int tb = task >> 5, kc = task & 31;
  const float* src = x + (size_t)(tb * 16 + n) * C_SZ + kc * 32 + quad * 8;
  float4 a = *(const float4*)src;
  float4 b = *(const float4*)(src + 4);
  ushort4v o0, o1;
  o0[0] = f2bf(a.x); o0[1] = f2bf(a.y); o0[2] = f2bf(a.z); o0[3] = f2bf(a.w);
  o1[0] = f2bf(b.x); o1[1] = f2bf(b.y); o1[2] = f2bf(b.z); o1[3] = f2bf(b.w);
  unsigned short* dst = Af + ((size_t)((tb * NKC + kc) * 4 + quad) * 16 + n) * 8;
  *(ushort4v*)dst = o0;
  *(ushort4v*)(dst + 4) = o1;
}

__device__ __forceinline__ void pack_w_task(const float* __restrict__ W,
                                            unsigned short* __restrict__ Wb,
                                            int N, int task, int lane) {
  const int quad = lane >> 4, n = lane & 15;
  const int nt = task >> 5, kc = task & 31;
  const int col = nt * 16 + n;
  const int k0 = kc * 32 + quad * 8;
  ushort4v o0, o1;
#pragma unroll
  for (int i = 0; i < 4; ++i) o0[i] = f2bf(W[(size_t)(k0 + i) * N + col]);
#pragma unroll
  for (int i = 0; i < 4; ++i) o1[i] = f2bf(W[(size_t)(k0 + 4 + i) * N + col]);
  unsigned short* dst = Wb + ((size_t)((nt * NKC + kc) * 4 + quad) * 16 + n) * 8;
  *(ushort4v*)dst = o0;
  *(ushort4v*)(dst + 4) = o1;
}

__global__ __launch_bounds__(256) void pack_all(
    const float* __restrict__ x, const float* __restrict__ Wa,
    const float* __restrict__ Wp, unsigned short* __restrict__ Af,
    unsigned short* __restrict__ Wab, unsigned short* __restrict__ Wpb) {
  const int bx = blockIdx.x;
  const int sub = threadIdx.x >> 6;
  const int lane = threadIdx.x & 63;
  if (bx < 4096) {
    pack_x_task(x, Af, bx * 4 + sub, lane);              // 512 tb x 32 kc
  } else if (bx < 4096 + 1536) {
    pack_w_task(Wa, Wab, C3_SZ, (bx - 4096) * 4 + sub, lane);  // 192 nt x 32
  } else {
    pack_w_task(Wp, Wpb, C_SZ, (bx - 5632) * 4 + sub, lane);   // 64 nt x 32
  }
}

// ---------------------------------------------------------------------------
// m97-style staged GEMM mainloop (verified round 6): 128x128 tile, BK=64,
// global_load_lds(16B) into an LDS image of the fragment-blocked layout.
// ---------------------------------------------------------------------------
__device__ __forceinline__ void gemm128_mainloop(
    const unsigned short* __restrict__ A, const unsigned short* __restrict__ B,
    int tbB, int ntB, unsigned short* smem, f32x4 acc[4][4]) {
  const int tid = threadIdx.x;
  const int w = tid >> 6, lane = tid & 63;
  const int quad = lane >> 4, n = lane & 15;
  const int wr = w >> 1, wc = w & 1;
  unsigned short* smemA = smem;         // 8192 shorts
  unsigned short* smemB = smem + 8192;  // 8192 shorts

  for (int kc0 = 0; kc0 < NKC; kc0 += 2) {
#pragma unroll
    for (int i2 = 0; i2 < 2; ++i2) {
      const int i = 2 * w + i2;
      const unsigned short* gA =
          A + ((size_t)(tbB + i) * NKC + kc0) * 512 + lane * 8;
      const unsigned short* gB =
          B + ((size_t)(ntB + i) * NKC + kc0) * 512 + lane * 8;
      gll16(gA, smemA + i * 1024);
      gll16(gA + 512, smemA + i * 1024 + 512);
      gll16(gB, smemB + i * 1024);
      gll16(gB + 512, smemB + i * 1024 + 512);
    }
    __syncthreads();
#pragma unroll
    for (int kcl = 0; kcl < 2; ++kcl) {
      bf16x8 af[4], bfr[4];
#pragma unroll
      for (int m = 0; m < 4; ++m)
        af[m] = *(const bf16x8*)(smemA + (wr * 4 + m) * 1024 +
                                 (kcl * 4 + quad) * 128 + n * 8);
#pragma unroll
      for (int nn = 0; nn < 4; ++nn)
        bfr[nn] = *(const bf16x8*)(smemB + (wc * 4 + nn) * 1024 +
                                   (kcl * 4 + quad) * 128 + n * 8);
#pragma unroll
      for (int m = 0; m < 4; ++m)
#pragma unroll
        for (int nn = 0; nn < 4; ++nn)
          acc[m][nn] = __builtin_amdgcn_mfma_f32_16x16x32_bf16(
              af[m], bfr[nn], acc[m][nn], 0, 0, 0);
    }
    __syncthreads();
  }
}

// qkv: 1-D grid 1536, XCD-aware swizzle — each XCD (f&7) owns 8 consecutive
// by rows; bx varies fastest so the 2 MB Af row stays hot in that XCD's L2
// while Wab streams.
__global__ __launch_bounds__(256) void qkv_mfma(
    const unsigned short* __restrict__ Af, const unsigned short* __restrict__ Wab,
    const float* __restrict__ bias, unsigned short* __restrict__ Qf,
    unsigned short* __restrict__ Kf, unsigned short* __restrict__ Vf) {
  __shared__ unsigned short smem[16384];
  const int tid = threadIdx.x;
  const int w = tid >> 6, lane = tid & 63;
  const int quad = lane >> 4, n = lane & 15;
  const int wr = w >> 1, wc = w & 1;
  const int f = blockIdx.x;
  const int xcd = f & 7, i = f >> 3;
  const int by = xcd * 8 + (i / 24);   // [0,64)
  const int bx = i % 24;               // [0,24)
  f32x4 acc[4][4];
#pragma unroll
  for (int m = 0; m < 4; ++m)
#pragma unroll
    for (int nn = 0; nn < 4; ++nn) acc[m][nn] = (f32x4){0.f, 0.f, 0.f, 0.f};

  gemm128_mainloop(Af, Wab, by * 8, bx * 8, smem, acc);

  const int cb = bx * 128 + wc * 64;
  const int which = cb >> 10;
  const int h = (cb & 1023) >> 6;
  const int gr0 = by * 128 + wr * 64;
  const int b = gr0 >> 11;
  const int t0 = gr0 & 2047;
  const size_t bhoff = (size_t)(b * H_SZ + h) * (T_SZ * D_SZ);
  float bfl[4];
#pragma unroll
  for (int nn = 0; nn < 4; ++nn) bfl[nn] = bias[cb + nn * 16 + n];

  if (which < 2) {
    unsigned short* dst = ((which == 0) ? Qf : Kf) + bhoff;
    // Q carries 1/sqrt(D) AND log2(e): softmax exp becomes a bare v_exp_f32
    const float scl = (which == 0) ? 0.18033688f : 1.0f;
#pragma unroll
    for (int m = 0; m < 4; ++m) {
      const int tb = (t0 + m * 16) >> 4;
#pragma unroll
      for (int nn = 0; nn < 4; ++nn) {
        const int dc = nn >> 1;
        const int qd = (nn & 1) * 2 + (n >> 3);
        const int jq = n & 7;
#pragma unroll
        for (int r = 0; r < 4; ++r) {
          const int nq = quad * 4 + r;
          dst[((size_t)((tb * 2 + dc) * 4 + qd)) * 128 + nq * 8 + jq] =
              f2bf((acc[m][nn][r] + bfl[nn]) * scl);
        }
      }
    }
  } else {
    unsigned short* dst = Vf + bhoff;
    const int gb0 = t0 >> 5;
#pragma unroll
    for (int m = 0; m < 4; ++m) {
      const int gb = gb0 + (m >> 1);
#pragma unroll
      for (int nn = 0; nn < 4; ++nn) {
#pragma unroll
        for (int r = 0; r < 4; ++r) {
          dst[((size_t)((gb * 4 + nn) * 4 + quad)) * 128 + n * 8 + (m & 1) * 4 + r] =
              f2bf(acc[m][nn][r] + bfl[nn]);
        }
      }
    }
  }
}

// proj: 1-D grid 512, same XCD swizzle (xcd owns 8 by rows, bx inner).
__global__ __launch_bounds__(256) void proj_mfma(
    const unsigned short* __restrict__ Yf, const unsigned short* __restrict__ Wpb,
    const float* __restrict__ bias, float* __restrict__ out) {
  __shared__ unsigned short smem[16384];
  const int tid = threadIdx.x;
  const int w = tid >> 6, lane = tid & 63;
  const int quad = lane >> 4, n = lane & 15;
  const int wr = w >> 1, wc = w & 1;
  const int f = blockIdx.x;
  const int xcd = f & 7, i = f >> 3;
  const int by = xcd * 8 + (i / 8);    // [0,64)
  const int bx = i % 8;                // [0,8)
  f32x4 acc[4][4];
#pragma unroll
  for (int m = 0; m < 4; ++m)
#pragma unroll
    for (int nn = 0; nn < 4; ++nn) acc[m][nn] = (f32x4){0.f, 0.f, 0.f, 0.f};

  gemm128_mainloop(Yf, Wpb, by * 8, bx * 8, smem, acc);

  const int cb = bx * 128 + wc * 64;
  const int gr0 = by * 128 + wr * 64;
  float bfl[4];
#pragma unroll
  for (int nn = 0; nn < 4; ++nn) bfl[nn] = bias[cb + nn * 16 + n];
#pragma unroll
  for (int m = 0; m < 4; ++m)
#pragma unroll
    for (int nn = 0; nn < 4; ++nn)
#pragma unroll
      for (int r = 0; r < 4; ++r)
        out[(size_t)(gr0 + m * 16 + quad * 4 + r) * C_SZ + cb + nn * 16 + n] =
            acc[m][nn][r] + bfl[nn];
}

// ---------------------------------------------------------------------------
// attn_mfma v7: v5 + V-prefetch (K and V both prefetched into dead registers
// after m=3), NO launch_bounds occupancy cap (round 8 showed the (64,4) cap
// forces a 64/64 VGPR/AGPR split and spills the accumulator to scratch).
// ---------------------------------------------------------------------------
__global__ __launch_bounds__(64) void attn_mfma(
    const unsigned short* __restrict__ Qf,
    const unsigned short* __restrict__ Kf,
    const unsigned short* __restrict__ Vf, unsigned short* __restrict__ Yf) {
  const int lane = threadIdx.x;
  const int quad = lane >> 4;
  const int n = lane & 15;
  const int bx = blockIdx.x;
  const int qt = 31 - (bx >> 6);  // long blocks dispatch first
  const int bh = bx & 63;
  const int b = bh >> 4, h = bh & 15;
  const int wq0 = qt * 64;
  const size_t bhoff = (size_t)bh * (T_SZ * D_SZ);
  const bf16x8* Qp = (const bf16x8*)(Qf + bhoff);
  const bf16x8* Kp = (const bf16x8*)(Kf + bhoff);
  const bf16x8* Vp = (const bf16x8*)(Vf + bhoff);

  bf16x8 qfr[4][2];
#pragma unroll
  for (int m = 0; m < 4; ++m) {
    const int tb = (wq0 >> 4) + m;
#pragma unroll
    for (int dc = 0; dc < 2; ++dc)
      qfr[m][dc] = Qp[((tb * 2 + dc) * 4 + quad) * 16 + n];
  }

  bf16x8 kfr[4][2], vfr[2][4];
  f32x4 O[4][4];
  f32x4 ls[4];
#pragma unroll
  for (int m = 0; m < 4; ++m) {
    ls[m] = (f32x4){0.f, 0.f, 0.f, 0.f};
#pragma unroll
    for (int dv = 0; dv < 4; ++dv) O[m][dv] = (f32x4){0.f, 0.f, 0.f, 0.f};
  }

  // preload K and V for tile 0
#pragma unroll
  for (int s = 0; s < 4; ++s) {
    kfr[s][0] = Kp[((s * 2 + 0) * 4 + quad) * 16 + n];
    kfr[s][1] = Kp[((s * 2 + 1) * 4 + quad) * 16 + n];
  }
#pragma unroll
  for (int g = 0; g < 2; ++g)
#pragma unroll
    for (int dv = 0; dv < 4; ++dv)
      vfr[g][dv] = Vp[((g * 4 + dv) * 4 + quad) * 16 + n];

  // ---- full (unmasked) k-tiles ----
  for (int kt = 0; kt < qt; ++kt) {
#pragma unroll
    for (int m = 0; m < 4; ++m) {
      f32x4 st[4];
#pragma unroll
      for (int s = 0; s < 4; ++s) {
        f32x4 z = {0.f, 0.f, 0.f, 0.f};
        z = __builtin_amdgcn_mfma_f32_16x16x32_bf16(kfr[s][0], qfr[m][0], z, 0, 0, 0);
        z = __builtin_amdgcn_mfma_f32_16x16x32_bf16(kfr[s][1], qfr[m][1], z, 0, 0, 0);
        st[s] = z;
      }
      if (m == 3) {
        // kfr dead for this tile: prefetch K for tile kt+1 (maybe diagonal)
        const int tb0 = (kt + 1) * 4;
#pragma unroll
        for (int s = 0; s < 4; ++s) {
          kfr[s][0] = Kp[(((tb0 + s) * 2 + 0) * 4 + quad) * 16 + n];
          kfr[s][1] = Kp[(((tb0 + s) * 2 + 1) * 4 + quad) * 16 + n];
        }
      }
      uint4v pw[2];
#pragma unroll
      for (int s = 0; s < 4; ++s) {
        float pr[4];
#pragma unroll
        for (int r = 0; r < 4; ++r) {
          pr[r] = __builtin_amdgcn_exp2f(st[s][r]);
          ls[m][r] += pr[r];
        }
        pw[s >> 1][(s & 1) * 2 + 0] = packbf2(pr[0], pr[1]);
        pw[s >> 1][(s & 1) * 2 + 1] = packbf2(pr[2], pr[3]);
      }
#pragma unroll
      for (int g = 0; g < 2; ++g) {
        const bf16x8 pg = __builtin_bit_cast(bf16x8, pw[g]);
#pragma unroll
        for (int dv = 0; dv < 4; ++dv)
          O[m][dv] = __builtin_amdgcn_mfma_f32_16x16x32_bf16(
              pg, vfr[g][dv], O[m][dv], 0, 0, 0);
      }
      if (m == 3) {
        // vfr dead after this tile's last PV: prefetch V for tile kt+1
        const int gb0 = (kt + 1) * 2;
#pragma unroll
        for (int g = 0; g < 2; ++g)
#pragma unroll
          for (int dv = 0; dv < 4; ++dv)
            vfr[g][dv] = Vp[(((gb0 + g) * 4 + dv) * 4 + quad) * 16 + n];
      }
    }
  }

  // ---- diagonal k-tile (kt == qt): kfr/vfr already resident ----
  {
#pragma unroll
    for (int m = 0; m < 4; ++m) {
      f32x4 st[4];
#pragma unroll
      for (int s = 0; s < 4; ++s) {
        f32x4 z = {0.f, 0.f, 0.f, 0.f};
        if (s <= m) {
          z = __builtin_amdgcn_mfma_f32_16x16x32_bf16(kfr[s][0], qfr[m][0], z, 0, 0, 0);
          z = __builtin_amdgcn_mfma_f32_16x16x32_bf16(kfr[s][1], qfr[m][1], z, 0, 0, 0);
        }
        st[s] = z;
      }
      uint4v pw[2] = {(uint4v){0, 0, 0, 0}, (uint4v){0, 0, 0, 0}};
#pragma unroll
      for (int s = 0; s < 4; ++s) {
        if (s <= m) {
          float pr[4];
#pragma unroll
          for (int r = 0; r < 4; ++r) {
            float v = st[s][r];
            if (s == m && quad * 4 + r > n) v = -1e30f;  // key > query
            pr[r] = __builtin_amdgcn_exp2f(v);
            ls[m][r] += pr[r];
          }
          pw[s >> 1][(s & 1) * 2 + 0] = packbf2(pr[0], pr[1]);
          pw[s >> 1][(s & 1) * 2 + 1] = packbf2(pr[2], pr[3]);
        }
      }
#pragma unroll
      for (int g = 0; g < 2; ++g) {
        if (g * 2 <= m) {
          const bf16x8 pg = __builtin_bit_cast(bf16x8, pw[g]);
#pragma unroll
          for (int dv = 0; dv < 4; ++dv)
            O[m][dv] = __builtin_amdgcn_mfma_f32_16x16x32_bf16(
                pg, vfr[g][dv], O[m][dv], 0, 0, 0);
        }
      }
    }
  }

  // ---- single deferred row-sum reduction + epilogue (bf16 A-frag Yf) ----
#pragma unroll
  for (int m = 0; m < 4; ++m) {
    float lt = ls[m][0] + ls[m][1] + ls[m][2] + ls[m][3];
    lt += __shfl_xor(lt, 16);
    lt += __shfl_xor(lt, 32);
    const float inv = 1.0f / lt;
    float iv[4];
#pragma unroll
    for (int r = 0; r < 4; ++r) iv[r] = __shfl(inv, quad * 4 + r);
    const int tb = (b * T_SZ + wq0 + m * 16) >> 4;
#pragma unroll
    for (int dv = 0; dv < 4; ++dv) {
      const int kc = h * 2 + (dv >> 1);
      const int qa = (dv & 1) * 2 + (n >> 3);
      const int ja = n & 7;
#pragma unroll
      for (int r = 0; r < 4; ++r) {
        const int na = quad * 4 + r;
        Yf[((size_t)((tb * NKC + kc) * 4 + qa)) * 128 + na * 8 + ja] =
            f2bf(O[m][dv][r] * iv[r]);
      }
    }
  }
}

// ---------------------------------------------------------------------------
extern "C" void kernel_launch(void* const* d_in, const int* in_sizes, int n_in,
                              void* d_out, int out_size, void* d_ws,
                              size_t ws_size, hipStream_t stream) {
  const float* x = (const float*)d_in[0];
  const float* W_attn = (const float*)d_in[1];
  const float* b_attn = (const float*)d_in[2];
  const float* W_proj = (const float*)d_in[3];
  const float* b_proj = (const float*)d_in[4];
  float* out = (float*)d_out;

  const size_t perbf = (size_t)B_SZ * H_SZ * T_SZ * D_SZ;  // 8M elems
  unsigned short* Af = (unsigned short*)d_ws;              // 16 MB
  unsigned short* Wab = Af + (size_t)BT_SZ * C_SZ;         // 6 MB
  unsigned short* Wpb = Wab + (size_t)C_SZ * C3_SZ;        // 2 MB
  unsigned short* Qf = Wpb + (size_t)C_SZ * C_SZ;          // 16 MB
  unsigned short* Kf = Qf + perbf;                         // 16 MB
  unsigned short* Vf = Kf + perbf;                         // 16 MB
  unsigned short* Yf = Vf + perbf;                         // 16 MB

  pack_all<<<6144, 256, 0, stream>>>(x, W_attn, W_proj, Af, Wab, Wpb);
  qkv_mfma<<<1536, 256, 0, stream>>>(Af, Wab, b_attn, Qf, Kf, Vf);
  attn_mfma<<<dim3(32 * B_SZ * H_SZ), 64, 0, stream>>>(Qf, Kf, Vf, Yf);
  proj_mfma<<<512, 256, 0, stream>>>(Yf, Wpb, b_proj, out);
}